// Round 10
// baseline (186.246 us; speedup 1.0000x reference)
//
#include <hip/hip_runtime.h>
#include <hip/hip_bf16.h>

#define DIM 1024
#define NH 16
#define HD 64
#define BB 2
#define SS 2048
#define MROWS (BB * SS)   // 4096
#define SCALE 0.03125f    // 1024^-0.5
#define SC_LOG2E 0.04508422002778011f  // SCALE * log2(e)

typedef unsigned short u16;
typedef unsigned int u32;
typedef __attribute__((ext_vector_type(8))) short short8;
typedef __attribute__((ext_vector_type(4))) float f32x4;
typedef __attribute__((ext_vector_type(2))) unsigned int u32x2;

#if __has_builtin(__builtin_amdgcn_exp2f)
#define EXP2(x) __builtin_amdgcn_exp2f(x)
#else
#define EXP2(x) __builtin_exp2f(x)
#endif

__device__ __forceinline__ u16 f2bf(float f) {
  union { float f; u32 u; } v; v.f = f;
  return (u16)((v.u + 0x7fffu + ((v.u >> 16) & 1u)) >> 16);
}

__device__ __forceinline__ u32 pack2bf(float a, float b) {
  union { __hip_bfloat162 h; u32 u; } cv;
  cv.h = __float22bfloat162_rn(make_float2(a, b));
  return cv.u;
}

// permlane swaps: dst high row <-> src low row (row=32 / row=16 lanes)
__device__ __forceinline__ void plswap32(u32& a, u32& b) {
#if __has_builtin(__builtin_amdgcn_permlane32_swap)
  u32x2 t = __builtin_amdgcn_permlane32_swap(a, b, false, false);
  a = t[0]; b = t[1];
#else
  asm("v_permlane32_swap_b32 %0, %1" : "+v"(a), "+v"(b));
#endif
}
__device__ __forceinline__ void plswap16(u32& a, u32& b) {
#if __has_builtin(__builtin_amdgcn_permlane16_swap)
  u32x2 t = __builtin_amdgcn_permlane16_swap(a, b, false, false);
  a = t[0]; b = t[1];
#else
  asm("v_permlane16_swap_b32 %0, %1" : "+v"(a), "+v"(b));
#endif
}

__device__ __forceinline__ void async16(const u16* g, u16* l) {
  __builtin_amdgcn_global_load_lds(
      (const __attribute__((address_space(1))) void*)(const void*)g,
      (__attribute__((address_space(3))) void*)(void*)l, 16, 0, 0);
}

__device__ __forceinline__ short8 ld8(const u16* p) { return *(const short8*)p; }

// ---------------- fp32 -> bf16 convert (vectorized) ----------------
__global__ void cvt_kernel(const float* __restrict__ in, u16* __restrict__ out, int n4) {
  int i = blockIdx.x * blockDim.x + threadIdx.x;
  if (i < n4) {
    float4 v = ((const float4*)in)[i];
    u32 lo = (u32)f2bf(v.x) | ((u32)f2bf(v.y) << 16);
    u32 hi = (u32)f2bf(v.z) | ((u32)f2bf(v.w) << 16);
    ((uint2*)out)[i] = make_uint2(lo, hi);
  }
}

// ------- transpose + convert: in fp32 [R][C] -> out bf16 [C][R] -------
__global__ void tconv_kernel(const float* __restrict__ in, u16* __restrict__ out, int R, int C) {
  __shared__ u16 t[64 * 65];
  int c0 = blockIdx.x * 64, r0 = blockIdx.y * 64;
  #pragma unroll
  for (int i = 0; i < 16; i++) {
    int j = i * 256 + threadIdx.x;
    int rr = j >> 6, cc = j & 63;
    t[rr * 65 + cc] = f2bf(in[(size_t)(r0 + rr) * C + c0 + cc]);
  }
  __syncthreads();
  #pragma unroll
  for (int i = 0; i < 16; i++) {
    int j = i * 256 + threadIdx.x;
    int oc = j >> 6, orr = j & 63;
    out[(size_t)(c0 + oc) * R + r0 + orr] = t[orr * 65 + oc];
  }
}

// ---- bf16 GEMM, BM=128 x BN={128,64}, BK=64 (unchanged from R9-passing) ----
template <int MODE, int BN, int NXB>
__global__ __launch_bounds__(256, (BN == 128 ? 2 : 3)) void gemm_bk64(
    const u16* __restrict__ A, const u16* __restrict__ Bt,
    const float* __restrict__ bias, void* __restrict__ C,
    u16* __restrict__ vT, int M, int N, int K) {
  constexpr int JN = BN / 32;              // B-frags / wave (4 or 2)
  constexpr int BTI = BN / 32;             // B staging iters
  constexpr int BUF = 8192 + BN * 64;      // u16 per buffer
  __shared__ __align__(16) u16 smem[2 * BUF];
  const int tid = threadIdx.x;
  const int w = tid >> 6, l = tid & 63;
  const int r = l & 15, q = l >> 4;
  const int nwg = gridDim.x;
  const int cpx = nwg >> 3;
  const int lin = blockIdx.x;
  const int swz = (lin & 7) * cpx + (lin >> 3);
  const int m0 = (swz / NXB) * 128, n0 = (swz % NXB) * BN;
  const int qm = (w & 1) * 64, qn = (w >> 1) * (BN / 2);

  const int gc = (l & 7) ^ (l >> 3);
  const size_t aoffb = (size_t)(m0 + w * 32 + (l >> 3)) * K + (size_t)gc * 8;
  const size_t boffb = (size_t)(n0 + w * (BN / 4) + (l >> 3)) * K + (size_t)gc * 8;
  const int xs = r & 7;                    // read-side row XOR

#define GSTAGE(K0, BASE) do {                                                    \
    u16* As_ = (BASE); u16* Bs_ = As_ + 8192;                                    \
    _Pragma("unroll")                                                            \
    for (int t = 0; t < 4; t++)                                                  \
      async16(A + aoffb + (size_t)t * 8 * K + (K0), As_ + w * 2048 + t * 512 + l * 8); \
    _Pragma("unroll")                                                            \
    for (int t = 0; t < BTI; t++)                                                \
      async16(Bt + boffb + (size_t)t * 8 * K + (K0), Bs_ + w * (BN * 16) + t * 512 + l * 8); \
  } while (0)

  f32x4 acc[4][JN] = {};
  GSTAGE(0, smem);
  __syncthreads();
  for (int k0 = 0; k0 < K; k0 += 64) {
    u16* As = smem + ((k0 >> 6) & 1) * BUF;
    u16* Bs = As + 8192;
    if (k0 + 64 < K) GSTAGE(k0 + 64, smem + ((((k0 >> 6) & 1) ^ 1) * BUF));
    short8 af[2][4], bfr[2][JN];
    #pragma unroll
    for (int kq = 0; kq < 2; kq++) {
      #pragma unroll
      for (int i = 0; i < 4; i++)
        af[kq][i] = ld8(&As[(qm + i * 16 + r) * 64 + (((kq * 4 + q) ^ xs) * 8)]);
      #pragma unroll
      for (int j = 0; j < JN; j++)
        bfr[kq][j] = ld8(&Bs[(qn + j * 16 + r) * 64 + (((kq * 4 + q) ^ xs) * 8)]);
    }
    #pragma unroll
    for (int kq = 0; kq < 2; kq++)
      #pragma unroll
      for (int i = 0; i < 4; i++)
        #pragma unroll
        for (int j = 0; j < JN; j++)
          acc[i][j] = __builtin_amdgcn_mfma_f32_16x16x32_bf16(af[kq][i], bfr[kq][j], acc[i][j], 0, 0, 0);
    __syncthreads();
  }
#undef GSTAGE
  #pragma unroll
  for (int i = 0; i < 4; i++) {
    int ro = m0 + qm + i * 16 + q * 4;
    #pragma unroll
    for (int j = 0; j < JN; j++) {
      int col = n0 + qn + j * 16 + r;
      float bv = bias[col];
      float v0 = acc[i][j][0] + bv, v1 = acc[i][j][1] + bv;
      float v2 = acc[i][j][2] + bv, v3 = acc[i][j][3] + bv;
      if (MODE == 1) {
        float* out = (float*)C;
        out[(size_t)(ro + 0) * N + col] = v0;
        out[(size_t)(ro + 1) * N + col] = v1;
        out[(size_t)(ro + 2) * N + col] = v2;
        out[(size_t)(ro + 3) * N + col] = v3;
      } else {
        int h = col / 192, wi = col - h * 192;
        if (wi >= 128) {
          int bb = ro >> 11, s = ro & 2047, d = wi - 128;
          uint2 pk = make_uint2(pack2bf(v0, v1), pack2bf(v2, v3));
          *(uint2*)&vT[((size_t)((bb * NH + h) * HD + d)) * SS + s] = pk;
        } else {
          u16* qk2 = (u16*)C;
          const float sc = (wi < 64) ? SC_LOG2E : 1.0f;  // pre-scale Q only
          qk2[(size_t)(ro + 0) * 2048 + h * 128 + wi] = f2bf(v0 * sc);
          qk2[(size_t)(ro + 1) * 2048 + h * 128 + wi] = f2bf(v1 * sc);
          qk2[(size_t)(ro + 2) * 2048 + h * 128 + wi] = f2bf(v2 * sc);
          qk2[(size_t)(ro + 3) * 2048 + h * 128 + wi] = f2bf(v3 * sc);
        }
      }
    }
  }
}

// ------------------------- fused attention v7 -------------------------
// attn6 reshaped for 2x occupancy (8 waves/SIMD):
//   q-tile 128 -> 64 rows/block (grid 1024 = 4 blocks/CU), KVBLK 128 -> 64
//   (LDS dbuf 32KB/block, 4x32=128KB/CU), per-wave state halved so
//   launch_bounds(512,8) holds the <=64-VGPR line for 32 waves/CU.
// Wave (wq,ws): wq = 16 q-rows, ws = 32-s half of the 64-s tile.
// All attn6 techniques carried: XOR chunk-swizzled K/V staging (both rows
// now 64 wide: gch=(l&7)^(l>>3) for both), prefetch dbuf + 1 barrier/tile,
// in-register P via permlane swaps, denominator via ones-MFMA, setprio,
// XCD-bijective block remap (32 q-blocks of one (b,h) pinned per XCD).
__global__ __launch_bounds__(512, 8) void attn7_kernel(
    const u16* __restrict__ qk2, const u16* __restrict__ vT,
    u16* __restrict__ attno) {
  __shared__ __align__(16) u16 smem[16384];  // 32KB: dbuf 2 x {Ks 8KB | Vs 8KB}
  const int tid = threadIdx.x;
  const int w = tid >> 6, l = tid & 63;
  const int r = l & 15, q = l >> 4;
  const int wq = w & 3, ws = w >> 2;
  // XCD-aware bijective swizzle of (q-block, h, b): 1024 blocks, 8 XCDs
  const int lin = blockIdx.x + 32 * (blockIdx.y + 16 * blockIdx.z);  // 0..1023
  const int k8 = lin & 7, jj = lin >> 3;      // jj 0..127
  const int bh = ((jj >> 5) << 3) + k8;       // 0..31, 4 bh per XCD group
  const int h = bh & 15, b = bh >> 4;
  const int q0 = (jj & 31) * 64;

  const u16* qb = qk2 + (size_t)b * SS * 2048;
  const u16* kB = qb + h * 128 + 64;
  const u16* vB = vT + (size_t)((b * NH + h) * HD) * SS;

  // Q fragments (B-operand): rows q0+wq*16+r, k = kq*32+q*8 (pre-scaled)
  short8 qf[2];
  #pragma unroll
  for (int kq = 0; kq < 2; kq++)
    qf[kq] = ld8(qb + (size_t)(q0 + wq * 16 + r) * 2048 + h * 128 + kq * 32 + q * 8);

  // staging: K row s = w*8+(l>>3), V row d = w*8+(l>>3); LDS slot l&7 holds
  // global chunk (l&7)^(row&7); row&7 == l>>3 for both.
  const int gch = (l & 7) ^ (l >> 3);

#define STAGE(KV0, DST) do {                                                     \
    u16* Kd_ = (DST); u16* Vd_ = Kd_ + 4096;                                     \
    async16(kB + (size_t)((KV0) + w * 8 + (l >> 3)) * 2048 + gch * 8,            \
            &Kd_[w * 512 + l * 8]);                                              \
    async16(vB + (size_t)(w * 8 + (l >> 3)) * SS + (KV0) + gch * 8,              \
            &Vd_[w * 512 + l * 8]);                                              \
  } while (0)

  const short8 vone = {0x3F80, 0x3F80, 0x3F80, 0x3F80, 0x3F80, 0x3F80, 0x3F80, 0x3F80};
  f32x4 oacc[4] = {};
  f32x4 den = {};

  STAGE(0, smem);            // prologue: tile 0 -> buf 0
  __syncthreads();

  for (int t = 0; t < 32; ++t) {
    u16* Ks = smem + (t & 1) * 8192;
    u16* Vs = Ks + 4096;
    if (t < 31) STAGE((t + 1) * 64, smem + (((t & 1) ^ 1) * 8192));  // prefetch

    // ---- S^T = K Q^T over own 32-s half ----
    f32x4 sacc[2] = {};
    #pragma unroll
    for (int j2 = 0; j2 < 2; j2++) {
      const u16* krow = &Ks[(ws * 32 + j2 * 16 + r) * 64];
      short8 a0 = ld8(krow + ((q ^ (r & 7)) * 8));
      short8 a1 = ld8(krow + (((4 + q) ^ (r & 7)) * 8));
      __builtin_amdgcn_s_setprio(1);
      sacc[j2] = __builtin_amdgcn_mfma_f32_16x16x32_bf16(a0, qf[0], sacc[j2], 0, 0, 0);
      sacc[j2] = __builtin_amdgcn_mfma_f32_16x16x32_bf16(a1, qf[1], sacc[j2], 0, 0, 0);
      __builtin_amdgcn_s_setprio(0);
    }
    // ---- P = exp2(S) in-register, redistribute via permlane swaps ----
    short8 pa;
    {
      u32 A0 = pack2bf(EXP2(sacc[0][0]), EXP2(sacc[0][1]));
      u32 A1 = pack2bf(EXP2(sacc[0][2]), EXP2(sacc[0][3]));
      u32 B0 = pack2bf(EXP2(sacc[1][0]), EXP2(sacc[1][1]));
      u32 B1 = pack2bf(EXP2(sacc[1][2]), EXP2(sacc[1][3]));
      plswap32(A0, B0);
      plswap32(A1, B1);
      plswap16(A0, B0);
      plswap16(A1, B1);
      union { short8 s8; u32 u[4]; } pk;
      pk.u[0] = A0; pk.u[1] = A1; pk.u[2] = B0; pk.u[3] = B1;
      pa = pk.s8;
    }
    // ---- O += P @ V (own 32-s half); denom via ones-MFMA ----
    __builtin_amdgcn_s_setprio(1);
    den = __builtin_amdgcn_mfma_f32_16x16x32_bf16(pa, vone, den, 0, 0, 0);
    #pragma unroll
    for (int dj = 0; dj < 4; dj++) {
      short8 vb = ld8(&Vs[(dj * 16 + r) * 64 + (((ws * 4 + q) ^ (r & 7)) * 8)]);
      oacc[dj] = __builtin_amdgcn_mfma_f32_16x16x32_bf16(pa, vb, oacc[dj], 0, 0, 0);
    }
    __builtin_amdgcn_s_setprio(0);
    __syncthreads();   // drains our prefetch + all waves done with this buf
  }
#undef STAGE

  // ---- cross-wave reduction between s-halves (LDS reused as f32 scratch) ----
  float* part = (float*)smem;            // [4 wq][2 half][32 d][20] f32
  float* dnf  = part + 8 * 32 * 20;      // [2 ws][4 wq][16] f32
  const int ho = 1 - ws;
  {
    const int wbase = (wq * 2 + ho) * 32;   // region owned by the partner
    if (ws == 0) {
      *(f32x4*)&part[(wbase + r) * 20 + q * 4]      = oacc[2];
      *(f32x4*)&part[(wbase + 16 + r) * 20 + q * 4] = oacc[3];
    } else {
      *(f32x4*)&part[(wbase + r) * 20 + q * 4]      = oacc[0];
      *(f32x4*)&part[(wbase + 16 + r) * 20 + q * 4] = oacc[1];
    }
    if (r == 0)
      *(f32x4*)&dnf[(ws * 4 + wq) * 16 + q * 4] = den;
  }
  __syncthreads();
  {
    const int rbase = (wq * 2 + ws) * 32;   // our own region (partner wrote it)
    f32x4 dt = *(f32x4*)&dnf[(ho * 4 + wq) * 16 + q * 4] + den;
    f32x4 oa = (ws == 0) ? oacc[0] : oacc[2];
    f32x4 ob = (ws == 0) ? oacc[1] : oacc[3];
    oa += *(f32x4*)&part[(rbase + r) * 20 + q * 4];
    ob += *(f32x4*)&part[(rbase + 16 + r) * 20 + q * 4];
    #pragma unroll
    for (int e = 0; e < 4; e++) {
      float di = 1.f / dt[e];
      int row = q0 + wq * 16 + q * 4 + e;
      u16* o = &attno[(size_t)(b * SS + row) * DIM + h * HD + ws * 32 + r];
      o[0]  = f2bf(oa[e] * di);
      o[16] = f2bf(ob[e] * di);
    }
  }
}

extern "C" void kernel_launch(void* const* d_in, const int* in_sizes, int n_in,
                              void* d_out, int out_size, void* d_ws, size_t ws_size,
                              hipStream_t stream) {
  const float* x      = (const float*)d_in[0];
  const float* w_qkv  = (const float*)d_in[1];
  const float* b_qkv  = (const float*)d_in[2];
  const float* w_proj = (const float*)d_in[3];
  const float* b_proj = (const float*)d_in[4];
  float* out = (float*)d_out;
  char* ws = (char*)d_ws;
  // workspace layout (48 MB total)
  u16* xb     = (u16*)(ws);                       // [4096,1024]       8 MB
  u16* wqkvT  = (u16*)(ws + ((size_t)8  << 20));  // [3072,1024]       6 MB
  u16* wprojT = (u16*)(ws + ((size_t)14 << 20));  // [1024,1024]       2 MB
  u16* qk2    = (u16*)(ws + ((size_t)16 << 20));  // [4096,2048] Q,K  16 MB
  u16* attno  = (u16*)(ws + ((size_t)32 << 20));  // [4096,1024]       8 MB
  u16* vT     = (u16*)(ws + ((size_t)40 << 20));  // [2,16,64,2048]    8 MB

  cvt_kernel<<<4096, 256, 0, stream>>>(x, xb, MROWS * DIM / 4);
  tconv_kernel<<<dim3(48, 16), 256, 0, stream>>>(w_qkv, wqkvT, DIM, 3 * DIM);
  tconv_kernel<<<dim3(16, 16), 256, 0, stream>>>(w_proj, wprojT, DIM, DIM);
  // QKV: 128x128 tiles, 32 row-panels x 24 col-panels = 768 blocks (%8==0)
  gemm_bk64<0, 128, 24><<<768, 256, 0, stream>>>(xb, wqkvT, b_qkv, qk2, vT, MROWS, 3 * DIM, DIM);
  attn7_kernel<<<dim3(32, NH, BB), 512, 0, stream>>>(qk2, vT, attno);
  // proj: 128x64 tiles, 32 x 16 = 512 blocks (3 blocks/CU)
  gemm_bk64<1, 64, 16><<<512, 256, 0, stream>>>(attno, wprojT, b_proj, out, nullptr, MROWS, DIM, DIM);
}